// Round 13
// baseline (245.141 us; speedup 1.0000x reference)
//
#include <hip/hip_runtime.h>
#include <stdint.h>

#define B_  8
#define T_  512
#define D_  1024
#define H_  16
#define DH  128
#define BH  128          // B_*H_
#define ND  2048         // H_*DV
#define BT  4096         // B_*T_

typedef __attribute__((ext_vector_type(8))) short          short8;
typedef __attribute__((ext_vector_type(8))) __bf16         bf16x8;
typedef __attribute__((ext_vector_type(4))) float          f32x4;
typedef __attribute__((ext_vector_type(4))) unsigned short ushort4v;

static __device__ __forceinline__ unsigned short f2bf(float f) {
  unsigned u = __builtin_bit_cast(unsigned, f);
  u += 0x7FFFu + ((u >> 16) & 1u);           // round-to-nearest-even
  return (unsigned short)(u >> 16);
}
static __device__ __forceinline__ float bf2f(unsigned short h) {
  unsigned u = ((unsigned)h) << 16;
  return __builtin_bit_cast(float, u);
}
static __device__ __forceinline__ f32x4 mfma16(short8 a, short8 b, f32x4 c) {
  return __builtin_amdgcn_mfma_f32_16x16x32_bf16(
      __builtin_bit_cast(bf16x8, a), __builtin_bit_cast(bf16x8, b), c, 0, 0, 0);
}
static __device__ __forceinline__ void gload16(const unsigned short* g, unsigned short* l) {
  __builtin_amdgcn_global_load_lds(
      (const __attribute__((address_space(1))) void*)g,
      (__attribute__((address_space(3))) void*)l, 16, 0, 0);
}

// swizzled stage for [ROWS][64] tiles (256-thread blocks): LDS linear, source col XOR'd
template <int ROWS>
static __device__ __forceinline__ void stage_sw64(unsigned short* lds,
                                                  const unsigned short* __restrict__ src,
                                                  long stride, int tid) {
#pragma unroll
  for (int it = 0; it < ROWS / 32; ++it) {
    int n = tid + it * 256;
    int r = n >> 3, c = (n & 7) ^ (r & 7);
    gload16(src + (long)r * stride + c * 8, lds + n * 8);
  }
}

// MR x NR frags from two swizzled [*][64] tiles (KD=64)
template <int MR, int NR>
static __device__ __forceinline__ void mfma_sw64(const unsigned short* As,
                                                 const unsigned short* Bs,
                                                 int a0, int b0, int lrow, int g,
                                                 f32x4 (*acc)[NR]) {
#pragma unroll
  for (int ks = 0; ks < 2; ++ks) {
    short8 a[MR], b[NR];
#pragma unroll
    for (int i = 0; i < MR; ++i) {
      int ra = a0 + i * 16 + lrow;
      int c = (ks * 4 + g) ^ (ra & 7);
      a[i] = *(const short8*)&As[ra * 64 + c * 8];
    }
#pragma unroll
    for (int j = 0; j < NR; ++j) {
      int rb = b0 + j * 16 + lrow;
      int c = (ks * 4 + g) ^ (rb & 7);
      b[j] = *(const short8*)&Bs[rb * 64 + c * 8];
    }
#pragma unroll
    for (int i = 0; i < MR; ++i)
#pragma unroll
      for (int j = 0; j < NR; ++j) acc[i][j] = mfma16(a[i], b[j], acc[i][j]);
  }
}

#define IDS4                             \
  const int tid  = threadIdx.x;          \
  const int lane = tid & 63;             \
  const int wid  = tid >> 6;             \
  const int lrow = lane & 15;            \
  const int lk8  = (lane >> 4) * 8;      \
  const int lr4  = (lane >> 4) * 4;      \
  const int lg   = lane >> 4;            \
  const int wm = wid >> 1, wn = wid & 1;

#define LTS 132   // padded f32 row stride for 128-wide epilogue LDS transpose
#define LTQ 68    // padded f32 row stride for 64-wide epilogue scratch

// ------------------- merged prep: X cvt + 4 weight transposes -------------------
__global__ __launch_bounds__(256) void k_prep(const float* __restrict__ X,
                                              unsigned short* __restrict__ Xb,
                                              const float* __restrict__ Wq,
                                              const float* __restrict__ Wk,
                                              const float* __restrict__ Wv,
                                              const float* __restrict__ Wp,
                                              unsigned short* __restrict__ WT,
                                              unsigned short* __restrict__ WpT) {
  __shared__ float tile[32][33];
  int bid = blockIdx.x;
  if (bid < 4096) {                          // X fp32 -> bf16, vectorized
    int i = bid * 256 + threadIdx.x;
    f32x4 v = ((const f32x4*)X)[i];
    ushort4v o;
    o.x = f2bf(v.x); o.y = f2bf(v.y); o.z = f2bf(v.z); o.w = f2bf(v.w);
    ((ushort4v*)Xb)[i] = o;
    return;
  }
  bid -= 4096;
  const int which = bid >> 11;               // 0..3
  const int local = bid & 2047;
  const float* in;
  unsigned short* outp;
  int R, C, bx, by;
  if (which < 3) {
    in = which == 0 ? Wq : (which == 1 ? Wk : Wv);
    outp = WT + (size_t)which * ND * D_;
    R = D_; C = ND; bx = local & 63; by = local >> 6;
  } else {
    in = Wp; outp = WpT;
    R = ND; C = D_; bx = local & 31; by = local >> 5;
  }
  int c0 = bx * 32, r0 = by * 32;
  int tx = threadIdx.x & 31, ty = threadIdx.x >> 5;
#pragma unroll
  for (int i = 0; i < 32; i += 8)
    tile[ty + i][tx] = in[(long)(r0 + ty + i) * C + (c0 + tx)];
  __syncthreads();
#pragma unroll
  for (int i = 0; i < 32; i += 8)
    outp[(long)(c0 + ty + i) * R + (r0 + tx)] = f2bf(tile[tx][ty + i]);
}

// ------------------- QKV projection: 128x128, swizzled LDS, V written transposed -------------------
__global__ __launch_bounds__(256) void k_proj8(const unsigned short* __restrict__ Xb,
                                               const unsigned short* __restrict__ WT,
                                               const float* __restrict__ bq,
                                               const float* __restrict__ bk,
                                               const float* __restrict__ bv,
                                               unsigned short* __restrict__ Qb,
                                               unsigned short* __restrict__ Kb,
                                               unsigned short* __restrict__ Vt) {
  __shared__ unsigned short As[128 * 64], Bs[128 * 64];   // 32 KB
  IDS4
  const int flat = blockIdx.x, xcd = flat & 7, local = flat >> 3;   // local 0..191
  const int nt = xcd * 6 + (local % 6);      // 0..47
  const int mt = local / 6;                  // 0..31
  const int m0 = mt * 128, n0 = nt * 128;

  f32x4 acc[4][4] = {};
  for (int kk = 0; kk < D_; kk += 64) {
    stage_sw64<128>(As, Xb + (long)m0 * D_ + kk, D_, tid);
    stage_sw64<128>(Bs, WT + (long)n0 * D_ + kk, D_, tid);
    __syncthreads();
    mfma_sw64<4, 4>(As, Bs, wm * 64, wn * 64, lrow, lg, acc);
    __syncthreads();
  }

  const int nb = n0 >> 11;   // 0:Q 1:K 2:V
  const float* biasp = nb == 0 ? bq : (nb == 1 ? bk : bv);
  const int hcol = (n0 & 2047) >> 7;
  if (nb < 2) {
    unsigned short* dst = nb == 0 ? Qb : Kb;
#pragma unroll
    for (int i = 0; i < 4; ++i)
#pragma unroll
      for (int j = 0; j < 4; ++j) {
        int cc = (n0 & 2047) + wn * 64 + j * 16 + lrow;
        int dd = cc & 127;
        float bias = biasp[cc];
#pragma unroll
        for (int r = 0; r < 4; ++r) {
          int m = m0 + wm * 64 + i * 16 + lr4 + r;
          int bb = m >> 9, tt = m & (T_ - 1);
          dst[((long)(bb * H_ + hcol) * T_ + tt) * DH + dd] = f2bf(acc[i][j][r] + bias);
        }
      }
  } else {
#pragma unroll
    for (int i = 0; i < 4; ++i)
#pragma unroll
      for (int j = 0; j < 4; ++j) {
        int cc = (n0 & 2047) + wn * 64 + j * 16 + lrow;
        int dd = cc & 127;
        float bias = biasp[cc];
#pragma unroll
        for (int r = 0; r < 4; ++r) {
          int m = m0 + wm * 64 + i * 16 + lr4 + r;
          int bb = m >> 9, tt = m & (T_ - 1);
          Vt[((long)(bb * H_ + hcol) * DH + dd) * T_ + tt] = f2bf(acc[i][j][r] + bias);
        }
      }
  }
}

// ------------------- pos-k: one block per q; swizzled As; ping-pong Pk pipeline -------------------
__global__ __launch_bounds__(256) void k_posk(const unsigned short* __restrict__ Qb,
                                              const float* __restrict__ Pk,
                                              unsigned short* __restrict__ att) {
  const int bid = blockIdx.x;
  const int q = (bid & 1) ? (T_ - 1 - (bid >> 1)) : (bid >> 1);   // load balance
  const int ktiles = (q >> 6) + 1;
  __shared__ unsigned short As[128 * 128];
  __shared__ unsigned short Bs[2][64 * 136];
  IDS4
  {  // swizzled As stage: rows=bh(128), 16 chunks/row
    const unsigned short* src = Qb + (long)q * DH;
#pragma unroll
    for (int it = 0; it < 8; ++it) {
      int n = tid + it * 256;
      int r = n >> 4, c = (n & 15) ^ (r & 7);
      gload16(src + (long)r * (T_ * DH) + c * 8, As + n * 8);
    }
  }
  f32x4 pv[8];
  const float* psrc = Pk + (long)q * T_ * DH;
  auto loadPk = [&](int kt) {
#pragma unroll
    for (int it = 0; it < 8; ++it) {
      int chunk = tid + it * 256;
      int r = chunk >> 5, c4 = (chunk & 31) * 4;
      pv[it] = *(const f32x4*)(psrc + (long)(kt * 64 + r) * DH + c4);
    }
  };
  auto writeB = [&](int buf) {
#pragma unroll
    for (int it = 0; it < 8; ++it) {
      int chunk = tid + it * 256;
      int r = chunk >> 5, c4 = (chunk & 31) * 4;
      ushort4v o;
      o.x = f2bf(pv[it].x); o.y = f2bf(pv[it].y); o.z = f2bf(pv[it].z); o.w = f2bf(pv[it].w);
      *(ushort4v*)&Bs[buf][r * 136 + c4] = o;
    }
  };
  loadPk(0);
  asm volatile("s_waitcnt vmcnt(0)" ::: "memory");   // As + Pk0 done
  writeB(0);
  asm volatile("s_waitcnt lgkmcnt(0)" ::: "memory");
  __builtin_amdgcn_s_barrier();
  for (int kt = 0; kt < ktiles; ++kt) {
    const bool pre = (kt + 1 < ktiles);
    if (pre) loadPk(kt + 1);
    f32x4 acc[4][2] = {};
#pragma unroll
    for (int ks = 0; ks < 4; ++ks) {
      short8 a[4], b[2];
#pragma unroll
      for (int i = 0; i < 4; ++i) {
        int ra = wm * 64 + i * 16 + lrow;
        int c = (ks * 4 + lg) ^ (ra & 7);
        a[i] = *(const short8*)&As[ra * 128 + c * 8];
      }
#pragma unroll
      for (int j = 0; j < 2; ++j)
        b[j] = *(const short8*)&Bs[kt & 1][(wn * 32 + j * 16 + lrow) * 136 + ks * 32 + lk8];
#pragma unroll
      for (int i = 0; i < 4; ++i)
#pragma unroll
        for (int j = 0; j < 2; ++j)
          acc[i][j] = mfma16(a[i], b[j], acc[i][j]);
    }
    if (pre) {
      asm volatile("s_waitcnt vmcnt(0)" ::: "memory");
      writeB((kt + 1) & 1);
    }
#pragma unroll
    for (int i = 0; i < 4; ++i)
#pragma unroll
      for (int j = 0; j < 2; ++j) {
        int k = kt * 64 + wn * 32 + j * 16 + lrow;
#pragma unroll
        for (int r = 0; r < 4; ++r) {
          int bh = wm * 64 + i * 16 + lr4 + r;
          att[((long)q * BH + bh) * T_ + k] = f2bf(acc[i][j][r]);
        }
      }
    asm volatile("s_waitcnt lgkmcnt(0)" ::: "memory");
    __builtin_amdgcn_s_barrier();
  }
}

// ------------------- FUSED QK^T + posk-bias + exp + PV: Q in regs, V dbuf, 3-barrier pipeline -------------------
__global__ __launch_bounds__(256) void k_qkv(const unsigned short* __restrict__ Qb,
                                             const unsigned short* __restrict__ Kb,
                                             const unsigned short* __restrict__ Vt,
                                             unsigned short* __restrict__ att,
                                             float* __restrict__ Sinv,
                                             unsigned short* __restrict__ Ybb) {
  const int bh = blockIdx.x & 127, pr = blockIdx.x >> 7;   // pr 0..3
  __shared__ unsigned short Ks[64 * 128];        // 16 KB (single, restaged after bar-A)
  __shared__ unsigned short Vs[2][128 * 64];     // 32 KB double-buffered
  __shared__ unsigned short Ps[64 * 72];         //  9 KB
  __shared__ float lt[64 * LTQ];                 // 17.4 KB
  __shared__ float sInv[64];
  const int tid = threadIdx.x;
  const int lane = tid & 63, wid = tid >> 6;
  const int wm = wid >> 1, wn = wid & 1;
  const int lrow = lane & 15, lk8 = (lane >> 4) * 8, lr4 = (lane >> 4) * 4;
  const int row = tid >> 2, c0 = (tid & 3) * 16;
  const float scale = 0.08838834764831845f;   // 1/sqrt(128)
  const int b = bh >> 4, h = bh & 15;

  auto stageK = [&](int kt) {
    const unsigned short* ksrc = Kb + ((long)bh * T_ + kt * 64) * DH;
#pragma unroll
    for (int it = 0; it < 4; ++it) {
      int n = tid + it * 256;
      int r = n >> 4, c = (n & 15) ^ (r & 7);
      gload16(ksrc + (long)r * DH + c * 8, Ks + n * 8);
    }
  };
  auto stageV = [&](int kt, int buf) {
    const unsigned short* vsrc = Vt + (long)bh * DH * T_ + kt * 64;
#pragma unroll
    for (int it = 0; it < 4; ++it) {
      int n = tid + it * 256;
      int r = n >> 3, c = (n & 7) ^ (r & 7);
      gload16(vsrc + (long)r * T_ + c * 8, Vs[buf] + n * 8);
    }
  };

  for (int pass = 0; pass < 2; ++pass) {
    const int qt = pass ? 7 - pr : pr;
    const int q0 = qt * 64, ktiles = qt + 1;
    const int qabs = q0 + row;
    unsigned short* arow = att + ((long)qabs * BH + bh) * T_;
    // Q fragments -> registers (held for the whole pass)
    short8 aq[2][4];
#pragma unroll
    for (int i = 0; i < 2; ++i)
#pragma unroll
      for (int ks = 0; ks < 4; ++ks)
        aq[i][ks] = *(const short8*)&Qb[((long)bh * T_ + q0 + wm * 32 + i * 16 + lrow) * DH + ks * 32 + lk8];
    // prologue: K0, V0
    stageK(0); stageV(0, 0);
    asm volatile("s_waitcnt vmcnt(0)" ::: "memory");
    __builtin_amdgcn_sched_barrier(0);
    __builtin_amdgcn_s_barrier();
    float ssum = 0.f;
    f32x4 accv[2][4] = {};
    int cur = 0;
    for (int kt = 0; kt < ktiles; ++kt) {
      const bool pre = (kt + 1 < ktiles);
      short8 pb0 = *(const short8*)(arow + kt * 64 + c0);
      short8 pb1 = *(const short8*)(arow + kt * 64 + c0 + 8);
      // ---- QK^T: Ks (swizzled) x Q-regs ----
      f32x4 acc[2][2] = {};
#pragma unroll
      for (int ks = 0; ks < 4; ++ks) {
        short8 bk2[2];
#pragma unroll
        for (int j = 0; j < 2; ++j) {
          int rb = wn * 32 + j * 16 + lrow;
          int c = (ks * 4 + (lane >> 4)) ^ (rb & 7);
          bk2[j] = *(const short8*)&Ks[rb * 128 + c * 8];
        }
#pragma unroll
        for (int i = 0; i < 2; ++i)
#pragma unroll
          for (int j = 0; j < 2; ++j)
            acc[i][j] = mfma16(aq[i][ks], bk2[j], acc[i][j]);
      }
#pragma unroll
      for (int i = 0; i < 2; ++i)
#pragma unroll
        for (int j = 0; j < 2; ++j)
#pragma unroll
          for (int r = 0; r < 4; ++r)
            lt[(wm * 32 + i * 16 + lr4 + r) * LTQ + wn * 32 + j * 16 + lrow] = acc[i][j][r];
      asm volatile("s_waitcnt lgkmcnt(0)" ::: "memory");
      __builtin_amdgcn_sched_barrier(0);
      __builtin_amdgcn_s_barrier();            // bar A: lt visible; all Ks reads done
      // issue next-tile stages (K into Ks — free now; V into other buffer)
      if (pre) { stageK(kt + 1); stageV(kt + 1, cur ^ 1); }
      // ---- exp + rowsum; write Ptilde to global att and LDS Ps ----
      short8 o0, o1;
#pragma unroll
      for (int jj = 0; jj < 8; ++jj) {
        int k = kt * 64 + c0 + jj;
        float e0 = (k <= qabs)
                   ? __expf((lt[row * LTQ + c0 + jj] + bf2f((unsigned short)pb0[jj])) * scale) : 0.f;
        float e1 = (k + 8 <= qabs)
                   ? __expf((lt[row * LTQ + c0 + 8 + jj] + bf2f((unsigned short)pb1[jj])) * scale) : 0.f;
        o0[jj] = (short)f2bf(e0);
        o1[jj] = (short)f2bf(e1);
        ssum += e0 + e1;
      }
      *(short8*)(arow + kt * 64 + c0) = o0;
      *(short8*)(arow + kt * 64 + c0 + 8) = o1;
      *(short8*)&Ps[row * 72 + c0] = o0;
      *(short8*)&Ps[row * 72 + c0 + 8] = o1;
      asm volatile("s_waitcnt lgkmcnt(0)" ::: "memory");
      __builtin_amdgcn_sched_barrier(0);
      __builtin_amdgcn_s_barrier();            // bar B: Ps visible
      // ---- PV accumulate: Ps x Vs[cur] ----
#pragma unroll
      for (int ks = 0; ks < 2; ++ks) {
        short8 ap[2], bv2[4];
#pragma unroll
        for (int i = 0; i < 2; ++i) {
          int ra = wm * 32 + i * 16 + lrow;
          ap[i] = *(const short8*)&Ps[ra * 72 + ks * 32 + lk8];
        }
#pragma unroll
        for (int j = 0; j < 4; ++j) {
          int rb = wn * 64 + j * 16 + lrow;
          int c = ((ks * 4) + (lane >> 4)) ^ (rb & 7);
          bv2[j] = *(const short8*)&Vs[cur][rb * 64 + c * 8];
        }
#pragma unroll
        for (int i = 0; i < 2; ++i)
#pragma unroll
          for (int j = 0; j < 4; ++j)
            accv[i][j] = mfma16(ap[i], bv2[j], accv[i][j]);
      }
      // bar C: next tile's K/V landed; PV reads (completed into regs) done
      if (pre) asm volatile("s_waitcnt vmcnt(0)" ::: "memory");
      asm volatile("s_waitcnt lgkmcnt(0)" ::: "memory");
      __builtin_amdgcn_sched_barrier(0);
      __builtin_amdgcn_s_barrier();
      cur ^= 1;
    }
    ssum += __shfl_xor(ssum, 1, 64);
    ssum += __shfl_xor(ssum, 2, 64);
    float si = 1.f / ssum;
    if ((tid & 3) == 0) { sInv[row] = si; Sinv[(long)qabs * BH + bh] = si; }
    __syncthreads();
#pragma unroll
    for (int i = 0; i < 2; ++i) {
      float sc2[4];
#pragma unroll
      for (int r = 0; r < 4; ++r) sc2[r] = sInv[wm * 32 + i * 16 + lr4 + r];
#pragma unroll
      for (int j = 0; j < 4; ++j) {
        int d = wn * 64 + j * 16 + lrow;
#pragma unroll
        for (int r = 0; r < 4; ++r) {
          int q = q0 + wm * 32 + i * 16 + lr4 + r;
          Ybb[(long)(b * T_ + q) * ND + h * DH + d] = f2bf(accv[i][j][r] * sc2[r]);
        }
      }
    }
    __syncthreads();                           // before next pass reuses Ks/Vs/sInv
  }
}

// ------------------- y += (Ptilde @ pos_v[q]) * Sinv; dbuf As + dbuf Pv pipeline -------------------
__global__ __launch_bounds__(256) void k_posv(const unsigned short* __restrict__ P,
                                              const float* __restrict__ Pv,
                                              const float* __restrict__ Sinv,
                                              unsigned short* __restrict__ Ybb) {
  const int bid = blockIdx.x;
  const int q = (bid & 1) ? (T_ - 1 - (bid >> 1)) : (bid >> 1);   // load balance
  const int ktiles = (q >> 6) + 1;
  __shared__ unsigned short As[2][128 * 64];   // 32 KB dbuf (P-tiles)
  __shared__ unsigned short Bs[2][128 * 72];   // 36 KB dbuf (Pv)
  __shared__ float lt[64 * LTQ];
  IDS4
  f32x4 pv[8];
  const float* psrc = Pv + (long)q * T_ * DH;
  auto loadPv = [&](int kt) {
#pragma unroll
    for (int it = 0; it < 8; ++it) {
      int chunk = tid + it * 256;
      int d4 = (chunk & 3) * 4 + ((chunk >> 6) & 7) * 16;
      int k  = ((chunk >> 2) & 15) + ((chunk >> 9) & 3) * 16;
      pv[it] = *(const f32x4*)(psrc + (long)(kt * 64 + k) * DH + d4);
    }
  };
  auto writeB = [&](int buf) {
#pragma unroll
    for (int it = 0; it < 8; ++it) {
      int chunk = tid + it * 256;
      int d4 = (chunk & 3) * 4 + ((chunk >> 6) & 7) * 16;
      int k  = ((chunk >> 2) & 15) + ((chunk >> 9) & 3) * 16;
      Bs[buf][(d4 + 0) * 72 + k] = f2bf(pv[it].x);
      Bs[buf][(d4 + 1) * 72 + k] = f2bf(pv[it].y);
      Bs[buf][(d4 + 2) * 72 + k] = f2bf(pv[it].z);
      Bs[buf][(d4 + 3) * 72 + k] = f2bf(pv[it].w);
    }
  };
  // prologue: As0 + Pv0
  stage_sw64<128>(As[0], P + (long)q * BH * T_, T_, tid);
  loadPv(0);
  asm volatile("s_waitcnt vmcnt(0)" ::: "memory");
  writeB(0);
  asm volatile("s_waitcnt lgkmcnt(0)" ::: "memory");
  __builtin_amdgcn_s_barrier();
  f32x4 acc[4][4] = {};
  for (int kt = 0; kt < ktiles; ++kt) {
    const bool pre = (kt + 1 < ktiles);
    if (pre) {
      stage_sw64<128>(As[(kt + 1) & 1], P + (long)q * BH * T_ + (kt + 1) * 64, T_, tid);  // 4 gloads
      loadPv(kt + 1);                                                                     // 8 loads
      // As[kt] was issued before these 12 -> counted wait leaves them in flight
      asm volatile("s_waitcnt vmcnt(12)" ::: "memory");
    } else {
      asm volatile("s_waitcnt vmcnt(0)" ::: "memory");
    }
    __builtin_amdgcn_s_barrier();              // As[kt] staged for all waves
    // A swizzled [128][64], B padded [128][72]
#pragma unroll
    for (int ks = 0; ks < 2; ++ks) {
      short8 a[4], b[4];
#pragma unroll
      for (int i = 0; i < 4; ++i) {
        int ra = wm * 64 + i * 16 + lrow;
        int c = (ks * 4 + lg) ^ (ra & 7);
        a[i] = *(const short8*)&As[kt & 1][ra * 64 + c * 8];
      }
#pragma unroll
      for (int j = 0; j < 4; ++j)
        b[j] = *(const short8*)&Bs[kt & 1][(wn * 64 + j * 16 + lrow) * 72 + ks * 32 + lk8];
#pragma unroll
      for (int i = 0; i < 4; ++i)
#pragma unroll
        for (int j = 0; j < 4; ++j)
          acc[i][j] = mfma16(a[i], b[j], acc[i][j]);
    }
    if (pre) writeB((kt + 1) & 1);             // compiler waits Pv regs (leaves gload_lds in flight)
    asm volatile("s_waitcnt lgkmcnt(0)" ::: "memory");
    __builtin_amdgcn_s_barrier();
  }
  // epilogue: 4 quarter-tiles (64bh x 64d) through padded scratch, vector RMW
  const int row = tid >> 2, c0 = (tid & 3) * 16;
#pragma unroll
  for (int hb = 0; hb < 2; ++hb)
#pragma unroll
    for (int hd = 0; hd < 2; ++hd) {
      int bh = hb * 64 + row;
      long idx = ((long)((bh >> 4) * T_ + q)) * ND + (bh & 15) * DH + hd * 64 + c0;
      short8 y0 = *(const short8*)&Ybb[idx];       // early issue
      short8 y1 = *(const short8*)&Ybb[idx + 8];
      float sc = Sinv[(long)q * BH + bh];
      if (wm == hb && wn == hd) {
#pragma unroll
        for (int i = 0; i < 4; ++i)
#pragma unroll
          for (int j = 0; j < 4; ++j)
#pragma unroll
            for (int r = 0; r < 4; ++r)
              lt[(i * 16 + lr4 + r) * LTQ + j * 16 + lrow] = acc[i][j][r];
      }
      __syncthreads();
      short8 o0, o1;
#pragma unroll
      for (int jj = 0; jj < 8; ++jj) {
        o0[jj] = (short)f2bf(lt[row * LTQ + c0 + jj] * sc + bf2f((unsigned short)y0[jj]));
        o1[jj] = (short)f2bf(lt[row * LTQ + c0 + 8 + jj] * sc + bf2f((unsigned short)y1[jj]));
      }
      *(short8*)&Ybb[idx] = o0;
      *(short8*)&Ybb[idx + 8] = o1;
      __syncthreads();
    }
}

// ------------------- out = Ybb @ Wp + bp: 128x128, swizzled operands, coalesced fp32 epilogue -------------------
__global__ __launch_bounds__(256) void k_oproj(const unsigned short* __restrict__ Ybb,
                                               const unsigned short* __restrict__ WpT,
                                               const float* __restrict__ bp,
                                               float* __restrict__ outp) {
  __shared__ unsigned short As[128 * 64], Bs[128 * 64];
  IDS4
  const int m0 = blockIdx.y * 128, n0 = blockIdx.x * 128;
  f32x4 acc[4][4] = {};
  for (int kk = 0; kk < ND; kk += 64) {
    stage_sw64<128>(As, Ybb + (long)m0 * ND + kk, ND, tid);
    stage_sw64<128>(Bs, WpT + (long)n0 * ND + kk, ND, tid);
    __syncthreads();
    mfma_sw64<4, 4>(As, Bs, wm * 64, wn * 64, lrow, lg, acc);
    __syncthreads();
  }
  float* lt = (float*)As;                 // [16][LTS]
  const int row = tid >> 4, c8 = (tid & 15) * 8;
  f32x4 b0 = *(const f32x4*)(bp + n0 + c8);
  f32x4 b1 = *(const f32x4*)(bp + n0 + c8 + 4);
#pragma unroll
  for (int rr = 0; rr < 8; ++rr) {
    if (wm == (rr >> 2)) {
      const int ii = rr & 3;
#pragma unroll
      for (int j = 0; j < 4; ++j)
#pragma unroll
        for (int r = 0; r < 4; ++r)
          lt[(lr4 + r) * LTS + wn * 64 + j * 16 + lrow] = acc[ii][j][r];
    }
    __syncthreads();
    f32x4 v0 = *(const f32x4*)&lt[row * LTS + c8];
    f32x4 v1 = *(const f32x4*)&lt[row * LTS + c8 + 4];
    int m = m0 + rr * 16 + row;
    v0.x += b0.x; v0.y += b0.y; v0.z += b0.z; v0.w += b0.w;
    v1.x += b1.x; v1.y += b1.y; v1.z += b1.z; v1.w += b1.w;
    *(f32x4*)&outp[(long)m * D_ + n0 + c8] = v0;
    *(f32x4*)&outp[(long)m * D_ + n0 + c8 + 4] = v1;
    __syncthreads();
  }
}

extern "C" void kernel_launch(void* const* d_in, const int* in_sizes, int n_in,
                              void* d_out, int out_size, void* d_ws, size_t ws_size,
                              hipStream_t stream) {
  const float* X  = (const float*)d_in[0];
  const float* Pk = (const float*)d_in[1];
  const float* Pv = (const float*)d_in[2];
  const float* Wq = (const float*)d_in[3];
  const float* bq = (const float*)d_in[4];
  const float* Wk = (const float*)d_in[5];
  const float* bk = (const float*)d_in[6];
  const float* Wv = (const float*)d_in[7];
  const float* bv = (const float*)d_in[8];
  const float* Wp = (const float*)d_in[9];
  const float* bp = (const float*)d_in[10];
  float* out = (float*)d_out;

  uint8_t* w = (uint8_t*)d_ws;
  unsigned short* Xb  = (unsigned short*)w; w += (size_t)BT * D_ * 2;      //  8 MB
  unsigned short* WT  = (unsigned short*)w; w += (size_t)3 * ND * D_ * 2;  // 12 MB
  unsigned short* WpT = (unsigned short*)w; w += (size_t)D_ * ND * 2;      //  4 MB
  unsigned short* Qb  = (unsigned short*)w; w += (size_t)BH * T_ * DH * 2; // 16 MB [bh][t][dh]
  unsigned short* Kb  = (unsigned short*)w; w += (size_t)BH * T_ * DH * 2; // 16 MB
  unsigned short* Vt  = (unsigned short*)w; w += (size_t)BH * DH * T_ * 2; // 16 MB [bh][dh][t]
  unsigned short* att = (unsigned short*)w; w += (size_t)T_ * BH * T_ * 2; // 67 MB
  unsigned short* Ybb = (unsigned short*)w; w += (size_t)BT * ND * 2;      // 16.7 MB
  float*          Sinv= (float*)w;          w += (size_t)T_ * BH * 4;      // 256 KB

  k_prep<<<12288, 256, 0, stream>>>(X, Xb, Wq, Wk, Wv, Wp, WT, WpT);
  k_proj8<<<1536, 256, 0, stream>>>(Xb, WT, bq, bk, bv, Qb, Kb, Vt);
  k_posk<<<T_, 256, 0, stream>>>(Qb, Pk, att);
  k_qkv<<<512, 256, 0, stream>>>(Qb, Kb, Vt, att, Sinv, Ybb);
  k_posv<<<T_, 256, 0, stream>>>(att, Pv, Sinv, Ybb);
  k_oproj<<<dim3(D_ / 128, BT / 128), 256, 0, stream>>>(Ybb, WpT, bp, out);
}

// Round 14
// 231.808 us; speedup vs baseline: 1.0575x; 1.0575x over previous
//
#include <hip/hip_runtime.h>
#include <stdint.h>

#define B_  8
#define T_  512
#define D_  1024
#define H_  16
#define DH  128
#define BH  128          // B_*H_
#define ND  2048         // H_*DV
#define BT  4096         // B_*T_

typedef __attribute__((ext_vector_type(8))) short          short8;
typedef __attribute__((ext_vector_type(8))) __bf16         bf16x8;
typedef __attribute__((ext_vector_type(4))) float          f32x4;
typedef __attribute__((ext_vector_type(4))) unsigned short ushort4v;

static __device__ __forceinline__ unsigned short f2bf(float f) {
  unsigned u = __builtin_bit_cast(unsigned, f);
  u += 0x7FFFu + ((u >> 16) & 1u);           // round-to-nearest-even
  return (unsigned short)(u >> 16);
}
static __device__ __forceinline__ float bf2f(unsigned short h) {
  unsigned u = ((unsigned)h) << 16;
  return __builtin_bit_cast(float, u);
}
static __device__ __forceinline__ f32x4 mfma16(short8 a, short8 b, f32x4 c) {
  return __builtin_amdgcn_mfma_f32_16x16x32_bf16(
      __builtin_bit_cast(bf16x8, a), __builtin_bit_cast(bf16x8, b), c, 0, 0, 0);
}
static __device__ __forceinline__ void gload16(const unsigned short* g, unsigned short* l) {
  __builtin_amdgcn_global_load_lds(
      (const __attribute__((address_space(1))) void*)g,
      (__attribute__((address_space(3))) void*)l, 16, 0, 0);
}

// swizzled stage for [ROWS][64] tiles (256-thread blocks): LDS linear, source col XOR'd
template <int ROWS>
static __device__ __forceinline__ void stage_sw64(unsigned short* lds,
                                                  const unsigned short* __restrict__ src,
                                                  long stride, int tid) {
#pragma unroll
  for (int it = 0; it < ROWS / 32; ++it) {
    int n = tid + it * 256;
    int r = n >> 3, c = (n & 7) ^ (r & 7);
    gload16(src + (long)r * stride + c * 8, lds + n * 8);
  }
}

// MR x NR frags from two swizzled [*][64] tiles (KD=64)
template <int MR, int NR>
static __device__ __forceinline__ void mfma_sw64(const unsigned short* As,
                                                 const unsigned short* Bs,
                                                 int a0, int b0, int lrow, int g,
                                                 f32x4 (*acc)[NR]) {
#pragma unroll
  for (int ks = 0; ks < 2; ++ks) {
    short8 a[MR], b[NR];
#pragma unroll
    for (int i = 0; i < MR; ++i) {
      int ra = a0 + i * 16 + lrow;
      int c = (ks * 4 + g) ^ (ra & 7);
      a[i] = *(const short8*)&As[ra * 64 + c * 8];
    }
#pragma unroll
    for (int j = 0; j < NR; ++j) {
      int rb = b0 + j * 16 + lrow;
      int c = (ks * 4 + g) ^ (rb & 7);
      b[j] = *(const short8*)&Bs[rb * 64 + c * 8];
    }
#pragma unroll
    for (int i = 0; i < MR; ++i)
#pragma unroll
      for (int j = 0; j < NR; ++j) acc[i][j] = mfma16(a[i], b[j], acc[i][j]);
  }
}

#define IDS4                             \
  const int tid  = threadIdx.x;          \
  const int lane = tid & 63;             \
  const int wid  = tid >> 6;             \
  const int lrow = lane & 15;            \
  const int lk8  = (lane >> 4) * 8;      \
  const int lr4  = (lane >> 4) * 4;      \
  const int lg   = lane >> 4;            \
  const int wm = wid >> 1, wn = wid & 1;

#define LTS 132   // padded f32 row stride for 128-wide epilogue LDS transpose
#define LTQ 68    // padded f32 row stride for 64-wide epilogue scratch

// ------------------- merged prep: X cvt + 4 weight transposes -------------------
__global__ __launch_bounds__(256) void k_prep(const float* __restrict__ X,
                                              unsigned short* __restrict__ Xb,
                                              const float* __restrict__ Wq,
                                              const float* __restrict__ Wk,
                                              const float* __restrict__ Wv,
                                              const float* __restrict__ Wp,
                                              unsigned short* __restrict__ WT,
                                              unsigned short* __restrict__ WpT) {
  __shared__ float tile[32][33];
  int bid = blockIdx.x;
  if (bid < 4096) {                          // X fp32 -> bf16, vectorized
    int i = bid * 256 + threadIdx.x;
    f32x4 v = ((const f32x4*)X)[i];
    ushort4v o;
    o.x = f2bf(v.x); o.y = f2bf(v.y); o.z = f2bf(v.z); o.w = f2bf(v.w);
    ((ushort4v*)Xb)[i] = o;
    return;
  }
  bid -= 4096;
  const int which = bid >> 11;               // 0..3
  const int local = bid & 2047;
  const float* in;
  unsigned short* outp;
  int R, C, bx, by;
  if (which < 3) {
    in = which == 0 ? Wq : (which == 1 ? Wk : Wv);
    outp = WT + (size_t)which * ND * D_;
    R = D_; C = ND; bx = local & 63; by = local >> 6;
  } else {
    in = Wp; outp = WpT;
    R = ND; C = D_; bx = local & 31; by = local >> 5;
  }
  int c0 = bx * 32, r0 = by * 32;
  int tx = threadIdx.x & 31, ty = threadIdx.x >> 5;
#pragma unroll
  for (int i = 0; i < 32; i += 8)
    tile[ty + i][tx] = in[(long)(r0 + ty + i) * C + (c0 + tx)];
  __syncthreads();
#pragma unroll
  for (int i = 0; i < 32; i += 8)
    outp[(long)(c0 + ty + i) * R + (r0 + tx)] = f2bf(tile[tx][ty + i]);
}

// ------------------- QKV projection: 128x128, swizzled LDS, V written transposed -------------------
__global__ __launch_bounds__(256) void k_proj8(const unsigned short* __restrict__ Xb,
                                               const unsigned short* __restrict__ WT,
                                               const float* __restrict__ bq,
                                               const float* __restrict__ bk,
                                               const float* __restrict__ bv,
                                               unsigned short* __restrict__ Qb,
                                               unsigned short* __restrict__ Kb,
                                               unsigned short* __restrict__ Vt) {
  __shared__ unsigned short As[128 * 64], Bs[128 * 64];   // 32 KB
  IDS4
  const int flat = blockIdx.x, xcd = flat & 7, local = flat >> 3;   // local 0..191
  const int nt = xcd * 6 + (local % 6);      // 0..47
  const int mt = local / 6;                  // 0..31
  const int m0 = mt * 128, n0 = nt * 128;

  f32x4 acc[4][4] = {};
  for (int kk = 0; kk < D_; kk += 64) {
    stage_sw64<128>(As, Xb + (long)m0 * D_ + kk, D_, tid);
    stage_sw64<128>(Bs, WT + (long)n0 * D_ + kk, D_, tid);
    __syncthreads();
    mfma_sw64<4, 4>(As, Bs, wm * 64, wn * 64, lrow, lg, acc);
    __syncthreads();
  }

  const int nb = n0 >> 11;   // 0:Q 1:K 2:V
  const float* biasp = nb == 0 ? bq : (nb == 1 ? bk : bv);
  const int hcol = (n0 & 2047) >> 7;
  if (nb < 2) {
    unsigned short* dst = nb == 0 ? Qb : Kb;
#pragma unroll
    for (int i = 0; i < 4; ++i)
#pragma unroll
      for (int j = 0; j < 4; ++j) {
        int cc = (n0 & 2047) + wn * 64 + j * 16 + lrow;
        int dd = cc & 127;
        float bias = biasp[cc];
#pragma unroll
        for (int r = 0; r < 4; ++r) {
          int m = m0 + wm * 64 + i * 16 + lr4 + r;
          int bb = m >> 9, tt = m & (T_ - 1);
          dst[((long)(bb * H_ + hcol) * T_ + tt) * DH + dd] = f2bf(acc[i][j][r] + bias);
        }
      }
  } else {
#pragma unroll
    for (int i = 0; i < 4; ++i)
#pragma unroll
      for (int j = 0; j < 4; ++j) {
        int cc = (n0 & 2047) + wn * 64 + j * 16 + lrow;
        int dd = cc & 127;
        float bias = biasp[cc];
#pragma unroll
        for (int r = 0; r < 4; ++r) {
          int m = m0 + wm * 64 + i * 16 + lr4 + r;
          int bb = m >> 9, tt = m & (T_ - 1);
          Vt[((long)(bb * H_ + hcol) * DH + dd) * T_ + tt] = f2bf(acc[i][j][r] + bias);
        }
      }
  }
}

// ------------------- pos-k: one block per q; CU-balanced q mapping; ping-pong Pk pipeline -------------------
__global__ __launch_bounds__(256) void k_posk(const unsigned short* __restrict__ Qb,
                                              const float* __restrict__ Pk,
                                              unsigned short* __restrict__ att) {
  const int bid = blockIdx.x;
  // CU-balanced: blocks bid and bid+256 co-reside on a CU (round-robin); their
  // ktiles sum to exactly 9: q(bid<256)=bid (1..4 tiles), q(bid>=256)=767-bid (5..8).
  const int q = (bid < 256) ? bid : 767 - bid;
  const int ktiles = (q >> 6) + 1;
  __shared__ unsigned short As[128 * 128];
  __shared__ unsigned short Bs[2][64 * 136];
  IDS4
  {  // swizzled As stage: rows=bh(128), 16 chunks/row
    const unsigned short* src = Qb + (long)q * DH;
#pragma unroll
    for (int it = 0; it < 8; ++it) {
      int n = tid + it * 256;
      int r = n >> 4, c = (n & 15) ^ (r & 7);
      gload16(src + (long)r * (T_ * DH) + c * 8, As + n * 8);
    }
  }
  f32x4 pv[8];
  const float* psrc = Pk + (long)q * T_ * DH;
  auto loadPk = [&](int kt) {
#pragma unroll
    for (int it = 0; it < 8; ++it) {
      int chunk = tid + it * 256;
      int r = chunk >> 5, c4 = (chunk & 31) * 4;
      pv[it] = *(const f32x4*)(psrc + (long)(kt * 64 + r) * DH + c4);
    }
  };
  auto writeB = [&](int buf) {
#pragma unroll
    for (int it = 0; it < 8; ++it) {
      int chunk = tid + it * 256;
      int r = chunk >> 5, c4 = (chunk & 31) * 4;
      ushort4v o;
      o.x = f2bf(pv[it].x); o.y = f2bf(pv[it].y); o.z = f2bf(pv[it].z); o.w = f2bf(pv[it].w);
      *(ushort4v*)&Bs[buf][r * 136 + c4] = o;
    }
  };
  loadPk(0);
  asm volatile("s_waitcnt vmcnt(0)" ::: "memory");   // As + Pk0 done
  writeB(0);
  asm volatile("s_waitcnt lgkmcnt(0)" ::: "memory");
  __builtin_amdgcn_s_barrier();
  for (int kt = 0; kt < ktiles; ++kt) {
    const bool pre = (kt + 1 < ktiles);
    if (pre) loadPk(kt + 1);
    f32x4 acc[4][2] = {};
#pragma unroll
    for (int ks = 0; ks < 4; ++ks) {
      short8 a[4], b[2];
#pragma unroll
      for (int i = 0; i < 4; ++i) {
        int ra = wm * 64 + i * 16 + lrow;
        int c = (ks * 4 + lg) ^ (ra & 7);
        a[i] = *(const short8*)&As[ra * 128 + c * 8];
      }
#pragma unroll
      for (int j = 0; j < 2; ++j)
        b[j] = *(const short8*)&Bs[kt & 1][(wn * 32 + j * 16 + lrow) * 136 + ks * 32 + lk8];
#pragma unroll
      for (int i = 0; i < 4; ++i)
#pragma unroll
        for (int j = 0; j < 2; ++j)
          acc[i][j] = mfma16(a[i], b[j], acc[i][j]);
    }
    if (pre) {
      asm volatile("s_waitcnt vmcnt(0)" ::: "memory");
      writeB((kt + 1) & 1);
    }
#pragma unroll
    for (int i = 0; i < 4; ++i)
#pragma unroll
      for (int j = 0; j < 2; ++j) {
        int k = kt * 64 + wn * 32 + j * 16 + lrow;
#pragma unroll
        for (int r = 0; r < 4; ++r) {
          int bh = wm * 64 + i * 16 + lr4 + r;
          att[((long)q * BH + bh) * T_ + k] = f2bf(acc[i][j][r]);
        }
      }
    asm volatile("s_waitcnt lgkmcnt(0)" ::: "memory");
    __builtin_amdgcn_s_barrier();
  }
}

// ------------------- FUSED QK^T + posk-bias + exp + PV: block per (bh, qt-pair) -------------------
__global__ __launch_bounds__(256) void k_qkv(const unsigned short* __restrict__ Qb,
                                             const unsigned short* __restrict__ Kb,
                                             const unsigned short* __restrict__ Vt,
                                             unsigned short* __restrict__ att,
                                             float* __restrict__ Sinv,
                                             unsigned short* __restrict__ Ybb) {
  const int bh = blockIdx.x & 127, pr = blockIdx.x >> 7;   // pr 0..3
  __shared__ unsigned short Qs[64 * 128], Ks[64 * 128], Vs[128 * 64];
  __shared__ unsigned short Ps[64 * 72];
  __shared__ float lt[64 * LTQ];
  __shared__ float sInv[64];
  const int tid = threadIdx.x;
  const int lane = tid & 63, wid = tid >> 6;
  const int wm = wid >> 1, wn = wid & 1;
  const int lrow = lane & 15, lk8 = (lane >> 4) * 8, lr4 = (lane >> 4) * 4;
  const int row = tid >> 2, c0 = (tid & 3) * 16;
  const float scale = 0.08838834764831845f;   // 1/sqrt(128)
  const int b = bh >> 4, h = bh & 15;

  for (int pass = 0; pass < 2; ++pass) {
    const int qt = pass ? 7 - pr : pr;
    const int q0 = qt * 64, ktiles = qt + 1;
    const int qabs = q0 + row;
    unsigned short* arow = att + ((long)qabs * BH + bh) * T_;
    {
      const unsigned short* src = Qb + ((long)bh * T_ + q0) * DH;
#pragma unroll
      for (int it = 0; it < 4; ++it) {
        int n = tid + it * 256;
        int r = n >> 4, c = (n & 15) ^ (r & 7);
        gload16(src + (long)r * DH + c * 8, Qs + n * 8);
      }
    }
    float ssum = 0.f;
    f32x4 accv[2][4] = {};
    for (int kt = 0; kt < ktiles; ++kt) {
      const unsigned short* ksrc = Kb + ((long)bh * T_ + kt * 64) * DH;
#pragma unroll
      for (int it = 0; it < 4; ++it) {
        int n = tid + it * 256;
        int r = n >> 4, c = (n & 15) ^ (r & 7);
        gload16(ksrc + (long)r * DH + c * 8, Ks + n * 8);
      }
      const unsigned short* vsrc = Vt + (long)bh * DH * T_ + kt * 64;
#pragma unroll
      for (int it = 0; it < 4; ++it) {
        int n = tid + it * 256;
        int r = n >> 3, c = (n & 7) ^ (r & 7);
        gload16(vsrc + (long)r * T_ + c * 8, Vs + n * 8);
      }
      short8 pb0 = *(const short8*)(arow + kt * 64 + c0);
      short8 pb1 = *(const short8*)(arow + kt * 64 + c0 + 8);
      __syncthreads();                       // drain staging, all tiles visible
      f32x4 acc[2][2] = {};
#pragma unroll
      for (int ks = 0; ks < 4; ++ks) {
        short8 aq[2], bk2[2];
#pragma unroll
        for (int i = 0; i < 2; ++i) {
          int ra = wm * 32 + i * 16 + lrow;
          int c = (ks * 4 + (lane >> 4)) ^ (ra & 7);
          aq[i] = *(const short8*)&Qs[ra * 128 + c * 8];
        }
#pragma unroll
        for (int j = 0; j < 2; ++j) {
          int rb = wn * 32 + j * 16 + lrow;
          int c = (ks * 4 + (lane >> 4)) ^ (rb & 7);
          bk2[j] = *(const short8*)&Ks[rb * 128 + c * 8];
        }
#pragma unroll
        for (int i = 0; i < 2; ++i)
#pragma unroll
          for (int j = 0; j < 2; ++j)
            acc[i][j] = mfma16(aq[i], bk2[j], acc[i][j]);
      }
#pragma unroll
      for (int i = 0; i < 2; ++i)
#pragma unroll
        for (int j = 0; j < 2; ++j)
#pragma unroll
          for (int r = 0; r < 4; ++r)
            lt[(wm * 32 + i * 16 + lr4 + r) * LTQ + wn * 32 + j * 16 + lrow] = acc[i][j][r];
      __syncthreads();
      short8 o0, o1;
#pragma unroll
      for (int jj = 0; jj < 8; ++jj) {
        int k = kt * 64 + c0 + jj;
        float e0 = (k <= qabs)
                   ? __expf((lt[row * LTQ + c0 + jj] + bf2f((unsigned short)pb0[jj])) * scale) : 0.f;
        float e1 = (k + 8 <= qabs)
                   ? __expf((lt[row * LTQ + c0 + 8 + jj] + bf2f((unsigned short)pb1[jj])) * scale) : 0.f;
        o0[jj] = (short)f2bf(e0);
        o1[jj] = (short)f2bf(e1);
        ssum += e0 + e1;
      }
      *(short8*)(arow + kt * 64 + c0) = o0;
      *(short8*)(arow + kt * 64 + c0 + 8) = o1;
      *(short8*)&Ps[row * 72 + c0] = o0;
      *(short8*)&Ps[row * 72 + c0 + 8] = o1;
      __syncthreads();
#pragma unroll
      for (int ks = 0; ks < 2; ++ks) {
        short8 ap[2], bv2[4];
#pragma unroll
        for (int i = 0; i < 2; ++i) {
          int ra = wm * 32 + i * 16 + lrow;
          ap[i] = *(const short8*)&Ps[ra * 72 + ks * 32 + lk8];
        }
#pragma unroll
        for (int j = 0; j < 4; ++j) {
          int rb = wn * 64 + j * 16 + lrow;
          int c = ((ks * 4) + (lane >> 4)) ^ (rb & 7);
          bv2[j] = *(const short8*)&Vs[rb * 64 + c * 8];
        }
#pragma unroll
        for (int i = 0; i < 2; ++i)
#pragma unroll
          for (int j = 0; j < 4; ++j)
            accv[i][j] = mfma16(ap[i], bv2[j], accv[i][j]);
      }
      __syncthreads();
    }
    ssum += __shfl_xor(ssum, 1, 64);
    ssum += __shfl_xor(ssum, 2, 64);
    float si = 1.f / ssum;
    if ((tid & 3) == 0) { sInv[row] = si; Sinv[(long)qabs * BH + bh] = si; }
    __syncthreads();
#pragma unroll
    for (int i = 0; i < 2; ++i) {
      float sc2[4];
#pragma unroll
      for (int r = 0; r < 4; ++r) sc2[r] = sInv[wm * 32 + i * 16 + lr4 + r];
#pragma unroll
      for (int j = 0; j < 4; ++j) {
        int d = wn * 64 + j * 16 + lrow;
#pragma unroll
        for (int r = 0; r < 4; ++r) {
          int q = q0 + wm * 32 + i * 16 + lr4 + r;
          Ybb[(long)(b * T_ + q) * ND + h * DH + d] = f2bf(accv[i][j][r] * sc2[r]);
        }
      }
    }
    __syncthreads();
  }
}

// ------------------- y += (Ptilde @ pos_v[q]) * Sinv; CU-balanced q; ping-pong Pv pipeline -------------------
__global__ __launch_bounds__(256) void k_posv(const unsigned short* __restrict__ P,
                                              const float* __restrict__ Pv,
                                              const float* __restrict__ Sinv,
                                              unsigned short* __restrict__ Ybb) {
  const int bid = blockIdx.x;
  const int q = (bid < 256) ? bid : 767 - bid;   // CU-balanced (sum 9 tiles per CU pair)
  const int ktiles = (q >> 6) + 1;
  __shared__ unsigned short As[128 * 64];
  __shared__ unsigned short Bs[2][128 * 72];
  __shared__ float lt[64 * LTQ];
  IDS4
  f32x4 pv[8];
  const float* psrc = Pv + (long)q * T_ * DH;
  auto loadPv = [&](int kt) {
#pragma unroll
    for (int it = 0; it < 8; ++it) {
      int chunk = tid + it * 256;
      int d4 = (chunk & 3) * 4 + ((chunk >> 6) & 7) * 16;
      int k  = ((chunk >> 2) & 15) + ((chunk >> 9) & 3) * 16;
      pv[it] = *(const f32x4*)(psrc + (long)(kt * 64 + k) * DH + d4);
    }
  };
  auto writeB = [&](int buf) {
#pragma unroll
    for (int it = 0; it < 8; ++it) {
      int chunk = tid + it * 256;
      int d4 = (chunk & 3) * 4 + ((chunk >> 6) & 7) * 16;
      int k  = ((chunk >> 2) & 15) + ((chunk >> 9) & 3) * 16;
      Bs[buf][(d4 + 0) * 72 + k] = f2bf(pv[it].x);
      Bs[buf][(d4 + 1) * 72 + k] = f2bf(pv[it].y);
      Bs[buf][(d4 + 2) * 72 + k] = f2bf(pv[it].z);
      Bs[buf][(d4 + 3) * 72 + k] = f2bf(pv[it].w);
    }
  };
  loadPv(0);
  asm volatile("s_waitcnt vmcnt(0)" ::: "memory");
  writeB(0);
  asm volatile("s_waitcnt lgkmcnt(0)" ::: "memory");
  __builtin_amdgcn_s_barrier();
  f32x4 acc[4][4] = {};
  for (int kt = 0; kt < ktiles; ++kt) {
    const bool pre = (kt + 1 < ktiles);
    stage_sw64<128>(As, P + (long)q * BH * T_ + kt * 64, T_, tid);    // 4 gloads swizzled
    if (pre) loadPv(kt + 1);                                          // 8 loads
    if (pre) asm volatile("s_waitcnt vmcnt(8)" ::: "memory");         // As done
    else     asm volatile("s_waitcnt vmcnt(0)" ::: "memory");
    __builtin_amdgcn_s_barrier();                                     // all As staged
    // A swizzled [128][64], B padded [128][72]
#pragma unroll
    for (int ks = 0; ks < 2; ++ks) {
      short8 a[4], b[4];
#pragma unroll
      for (int i = 0; i < 4; ++i) {
        int ra = wm * 64 + i * 16 + lrow;
        int c = (ks * 4 + lg) ^ (ra & 7);
        a[i] = *(const short8*)&As[ra * 64 + c * 8];
      }
#pragma unroll
      for (int j = 0; j < 4; ++j)
        b[j] = *(const short8*)&Bs[kt & 1][(wn * 64 + j * 16 + lrow) * 72 + ks * 32 + lk8];
#pragma unroll
      for (int i = 0; i < 4; ++i)
#pragma unroll
        for (int j = 0; j < 4; ++j)
          acc[i][j] = mfma16(a[i], b[j], acc[i][j]);
    }
    if (pre) {
      asm volatile("s_waitcnt vmcnt(0)" ::: "memory");
      writeB((kt + 1) & 1);
    }
    asm volatile("s_waitcnt lgkmcnt(0)" ::: "memory");
    __builtin_amdgcn_s_barrier();
  }
  // epilogue: 4 quarter-tiles (64bh x 64d) through padded scratch, vector RMW
  const int row = tid >> 2, c0 = (tid & 3) * 16;
#pragma unroll
  for (int hb = 0; hb < 2; ++hb)
#pragma unroll
    for (int hd = 0; hd < 2; ++hd) {
      int bh = hb * 64 + row;
      long idx = ((long)((bh >> 4) * T_ + q)) * ND + (bh & 15) * DH + hd * 64 + c0;
      short8 y0 = *(const short8*)&Ybb[idx];       // early issue
      short8 y1 = *(const short8*)&Ybb[idx + 8];
      float sc = Sinv[(long)q * BH + bh];
      if (wm == hb && wn == hd) {
#pragma unroll
        for (int i = 0; i < 4; ++i)
#pragma unroll
          for (int j = 0; j < 4; ++j)
#pragma unroll
            for (int r = 0; r < 4; ++r)
              lt[(i * 16 + lr4 + r) * LTQ + j * 16 + lrow] = acc[i][j][r];
      }
      __syncthreads();
      short8 o0, o1;
#pragma unroll
      for (int jj = 0; jj < 8; ++jj) {
        o0[jj] = (short)f2bf(lt[row * LTQ + c0 + jj] * sc + bf2f((unsigned short)y0[jj]));
        o1[jj] = (short)f2bf(lt[row * LTQ + c0 + 8 + jj] * sc + bf2f((unsigned short)y1[jj]));
      }
      *(short8*)&Ybb[idx] = o0;
      *(short8*)&Ybb[idx + 8] = o1;
      __syncthreads();
    }
}

// ------------------- out = Ybb @ Wp + bp: 128x128, swizzled operands, coalesced fp32 epilogue -------------------
__global__ __launch_bounds__(256) void k_oproj(const unsigned short* __restrict__ Ybb,
                                               const unsigned short* __restrict__ WpT,
                                               const float* __restrict__ bp,
                                               float* __restrict__ outp) {
  __shared__ unsigned short As[128 * 64], Bs[128 * 64];
  IDS4
  const int m0 = blockIdx.y * 128, n0 = blockIdx.x * 128;
  f32x4 acc[4][4] = {};
  for (int kk = 0; kk < ND; kk += 64) {
    stage_sw64<128>(As, Ybb + (long)m0 * ND + kk, ND, tid);
    stage_sw64<128>(Bs, WpT + (long)n0 * ND + kk, ND, tid);
    __syncthreads();
    mfma_sw64<4, 4>(As, Bs, wm * 64, wn * 64, lrow, lg, acc);
    __syncthreads();
  }
  float* lt = (float*)As;                 // [16][LTS]
  const int row = tid >> 4, c8 = (tid & 15) * 8;
  f32x4 b0 = *(const f32x4*)(bp + n0 + c8);
  f32x4 b1 = *(const f32x4*)(bp + n0 + c8 + 4);
#pragma unroll
  for (int rr = 0; rr < 8; ++rr) {
    if (wm == (rr >> 2)) {
      const int ii = rr & 3;
#pragma unroll
      for (int j = 0; j < 4; ++j)
#pragma unroll
        for (int r = 0; r < 4; ++r)
          lt[(lr4 + r) * LTS + wn * 64 + j * 16 + lrow] = acc[ii][j][r];
    }
    __syncthreads();
    f32x4 v0 = *(const f32x4*)&lt[row * LTS + c8];
    f32x4 v1 = *(const f32x4*)&lt[row * LTS + c8 + 4];
    int m = m0 + rr * 16 + row;
    v0.x += b0.x; v0.y += b0.y; v0.z += b0.z; v0.w += b0.w;
    v1.x += b1.x; v1.y += b1.y; v1.z += b1.z; v1.w += b1.w;
    *(f32x4*)&outp[(long)m * D_ + n0 + c8] = v0;
    *(f32x4*)&outp[(long)m * D_ + n0 + c8 + 4] = v1;
    __syncthreads();
  }
}

extern "C" void kernel_launch(void* const* d_in, const int* in_sizes, int n_in,
                              void* d_out, int out_size, void* d_ws, size_t ws_size,
                              hipStream_t stream) {
  const float* X  = (const float*)d_in[0];
  const float* Pk = (const float*)d_in[1];
  const float* Pv = (const float*)d_in[2];
  const float* Wq = (const float*)d_in[3];
  const float* bq = (const float*)d_in[4];
  const float* Wk = (const float*)d_in[5];
  const float* bk = (const float*)d_in[6];
  const float* Wv = (const float*)d_in[7];
  const float* bv = (const float*)d_in[8];
  const float* Wp = (const float*)d_in[9];
  const float* bp = (const float*)d_in[10];
  float* out = (float*)d_out;

  uint8_t* w = (uint8_t*)d_ws;
  unsigned short* Xb  = (unsigned short*)w; w += (size_t)BT * D_ * 2;      //  8 MB
  unsigned short* WT  = (unsigned short*)w; w += (size_t)3 * ND * D_ * 2;  // 12 MB
  unsigned short* WpT = (unsigned short*)w; w += (size_t)D_ * ND * 2;      //  4 MB
  unsigned short* Qb  = (unsigned short*)w; w += (size_t)BH * T_ * DH * 2; // 16 MB [bh][t][dh]
  unsigned short* Kb  = (unsigned short*)w; w += (size_t)BH * T_ * DH * 2; // 16 MB
  unsigned short* Vt  = (unsigned short*)w; w += (size_t)BH * DH * T_ * 2; // 16 MB [bh][dh][t]
  unsigned short* att = (unsigned short*)w; w += (size_t)T_ * BH * T_ * 2; // 67 MB
  unsigned short* Ybb = (unsigned short*)w; w += (size_t)BT * ND * 2;      // 16.7 MB
  float*          Sinv= (float*)w;          w += (size_t)T_ * BH * 4;      // 256 KB

  k_prep<<<12288, 256, 0, stream>>>(X, Xb, Wq, Wk, Wv, Wp, WT, WpT);
  k_proj8<<<1536, 256, 0, stream>>>(Xb, WT, bq, bk, bv, Qb, Kb, Vt);
  k_posk<<<T_, 256, 0, stream>>>(Qb, Pk, att);
  k_qkv<<<512, 256, 0, stream>>>(Qb, Kb, Vt, att, Sinv, Ybb);
  k_posv<<<T_, 256, 0, stream>>>(att, Pv, Sinv, Ybb);
  k_oproj<<<dim3(D_ / 128, BT / 128), 256, 0, stream>>>(Ybb, WpT, bp, out);
}

// Round 15
// 231.480 us; speedup vs baseline: 1.0590x; 1.0014x over previous
//
#include <hip/hip_runtime.h>
#include <stdint.h>

#define B_  8
#define T_  512
#define D_  1024
#define H_  16
#define DH  128
#define BH  128          // B_*H_
#define ND  2048         // H_*DV
#define BT  4096         // B_*T_

typedef __attribute__((ext_vector_type(8))) short          short8;
typedef __attribute__((ext_vector_type(8))) __bf16         bf16x8;
typedef __attribute__((ext_vector_type(4))) float          f32x4;
typedef __attribute__((ext_vector_type(4))) unsigned short ushort4v;

static __device__ __forceinline__ unsigned short f2bf(float f) {
  unsigned u = __builtin_bit_cast(unsigned, f);
  u += 0x7FFFu + ((u >> 16) & 1u);           // round-to-nearest-even
  return (unsigned short)(u >> 16);
}
static __device__ __forceinline__ float bf2f(unsigned short h) {
  unsigned u = ((unsigned)h) << 16;
  return __builtin_bit_cast(float, u);
}
static __device__ __forceinline__ f32x4 mfma16(short8 a, short8 b, f32x4 c) {
  return __builtin_amdgcn_mfma_f32_16x16x32_bf16(
      __builtin_bit_cast(bf16x8, a), __builtin_bit_cast(bf16x8, b), c, 0, 0, 0);
}
static __device__ __forceinline__ void gload16(const unsigned short* g, unsigned short* l) {
  __builtin_amdgcn_global_load_lds(
      (const __attribute__((address_space(1))) void*)g,
      (__attribute__((address_space(3))) void*)l, 16, 0, 0);
}

// swizzled stage for [ROWS][64] tiles (256-thread blocks): LDS linear, source col XOR'd
template <int ROWS>
static __device__ __forceinline__ void stage_sw64(unsigned short* lds,
                                                  const unsigned short* __restrict__ src,
                                                  long stride, int tid) {
#pragma unroll
  for (int it = 0; it < ROWS / 32; ++it) {
    int n = tid + it * 256;
    int r = n >> 3, c = (n & 7) ^ (r & 7);
    gload16(src + (long)r * stride + c * 8, lds + n * 8);
  }
}

// MR x NR frags from two swizzled [*][64] tiles (KD=64)
template <int MR, int NR>
static __device__ __forceinline__ void mfma_sw64(const unsigned short* As,
                                                 const unsigned short* Bs,
                                                 int a0, int b0, int lrow, int g,
                                                 f32x4 (*acc)[NR]) {
#pragma unroll
  for (int ks = 0; ks < 2; ++ks) {
    short8 a[MR], b[NR];
#pragma unroll
    for (int i = 0; i < MR; ++i) {
      int ra = a0 + i * 16 + lrow;
      int c = (ks * 4 + g) ^ (ra & 7);
      a[i] = *(const short8*)&As[ra * 64 + c * 8];
    }
#pragma unroll
    for (int j = 0; j < NR; ++j) {
      int rb = b0 + j * 16 + lrow;
      int c = (ks * 4 + g) ^ (rb & 7);
      b[j] = *(const short8*)&Bs[rb * 64 + c * 8];
    }
#pragma unroll
    for (int i = 0; i < MR; ++i)
#pragma unroll
      for (int j = 0; j < NR; ++j) acc[i][j] = mfma16(a[i], b[j], acc[i][j]);
  }
}

#define IDS4                             \
  const int tid  = threadIdx.x;          \
  const int lane = tid & 63;             \
  const int wid  = tid >> 6;             \
  const int lrow = lane & 15;            \
  const int lk8  = (lane >> 4) * 8;      \
  const int lr4  = (lane >> 4) * 4;      \
  const int lg   = lane >> 4;            \
  const int wm = wid >> 1, wn = wid & 1;

#define LTS 132   // padded f32 row stride for 128-wide epilogue LDS transpose
#define LTQ 68    // padded f32 row stride for 64-wide epilogue scratch

// ------------------- merged prep: X cvt + 4 weight transposes -------------------
__global__ __launch_bounds__(256) void k_prep(const float* __restrict__ X,
                                              unsigned short* __restrict__ Xb,
                                              const float* __restrict__ Wq,
                                              const float* __restrict__ Wk,
                                              const float* __restrict__ Wv,
                                              const float* __restrict__ Wp,
                                              unsigned short* __restrict__ WT,
                                              unsigned short* __restrict__ WpT) {
  __shared__ float tile[32][33];
  int bid = blockIdx.x;
  if (bid < 4096) {                          // X fp32 -> bf16, vectorized
    int i = bid * 256 + threadIdx.x;
    f32x4 v = ((const f32x4*)X)[i];
    ushort4v o;
    o.x = f2bf(v.x); o.y = f2bf(v.y); o.z = f2bf(v.z); o.w = f2bf(v.w);
    ((ushort4v*)Xb)[i] = o;
    return;
  }
  bid -= 4096;
  const int which = bid >> 11;               // 0..3
  const int local = bid & 2047;
  const float* in;
  unsigned short* outp;
  int R, C, bx, by;
  if (which < 3) {
    in = which == 0 ? Wq : (which == 1 ? Wk : Wv);
    outp = WT + (size_t)which * ND * D_;
    R = D_; C = ND; bx = local & 63; by = local >> 6;
  } else {
    in = Wp; outp = WpT;
    R = ND; C = D_; bx = local & 31; by = local >> 5;
  }
  int c0 = bx * 32, r0 = by * 32;
  int tx = threadIdx.x & 31, ty = threadIdx.x >> 5;
#pragma unroll
  for (int i = 0; i < 32; i += 8)
    tile[ty + i][tx] = in[(long)(r0 + ty + i) * C + (c0 + tx)];
  __syncthreads();
#pragma unroll
  for (int i = 0; i < 32; i += 8)
    outp[(long)(c0 + ty + i) * R + (r0 + tx)] = f2bf(tile[tx][ty + i]);
}

// ------------------- QKV projection: 128x128, swizzled LDS, V written transposed -------------------
__global__ __launch_bounds__(256) void k_proj8(const unsigned short* __restrict__ Xb,
                                               const unsigned short* __restrict__ WT,
                                               const float* __restrict__ bq,
                                               const float* __restrict__ bk,
                                               const float* __restrict__ bv,
                                               unsigned short* __restrict__ Qb,
                                               unsigned short* __restrict__ Kb,
                                               unsigned short* __restrict__ Vt) {
  __shared__ unsigned short As[128 * 64], Bs[128 * 64];   // 32 KB
  IDS4
  const int flat = blockIdx.x, xcd = flat & 7, local = flat >> 3;   // local 0..191
  const int nt = xcd * 6 + (local % 6);      // 0..47
  const int mt = local / 6;                  // 0..31
  const int m0 = mt * 128, n0 = nt * 128;

  f32x4 acc[4][4] = {};
  for (int kk = 0; kk < D_; kk += 64) {
    stage_sw64<128>(As, Xb + (long)m0 * D_ + kk, D_, tid);
    stage_sw64<128>(Bs, WT + (long)n0 * D_ + kk, D_, tid);
    __syncthreads();
    mfma_sw64<4, 4>(As, Bs, wm * 64, wn * 64, lrow, lg, acc);
    __syncthreads();
  }

  const int nb = n0 >> 11;   // 0:Q 1:K 2:V
  const float* biasp = nb == 0 ? bq : (nb == 1 ? bk : bv);
  const int hcol = (n0 & 2047) >> 7;
  if (nb < 2) {
    unsigned short* dst = nb == 0 ? Qb : Kb;
#pragma unroll
    for (int i = 0; i < 4; ++i)
#pragma unroll
      for (int j = 0; j < 4; ++j) {
        int cc = (n0 & 2047) + wn * 64 + j * 16 + lrow;
        int dd = cc & 127;
        float bias = biasp[cc];
#pragma unroll
        for (int r = 0; r < 4; ++r) {
          int m = m0 + wm * 64 + i * 16 + lr4 + r;
          int bb = m >> 9, tt = m & (T_ - 1);
          dst[((long)(bb * H_ + hcol) * T_ + tt) * DH + dd] = f2bf(acc[i][j][r] + bias);
        }
      }
  } else {
#pragma unroll
    for (int i = 0; i < 4; ++i)
#pragma unroll
      for (int j = 0; j < 4; ++j) {
        int cc = (n0 & 2047) + wn * 64 + j * 16 + lrow;
        int dd = cc & 127;
        float bias = biasp[cc];
#pragma unroll
        for (int r = 0; r < 4; ++r) {
          int m = m0 + wm * 64 + i * 16 + lr4 + r;
          int bb = m >> 9, tt = m & (T_ - 1);
          Vt[((long)(bb * H_ + hcol) * DH + dd) * T_ + tt] = f2bf(acc[i][j][r] + bias);
        }
      }
  }
}

// ------------------- pos-k: one block per q; CU-balanced q mapping; ping-pong Pk pipeline -------------------
__global__ __launch_bounds__(256) void k_posk(const unsigned short* __restrict__ Qb,
                                              const float* __restrict__ Pk,
                                              unsigned short* __restrict__ att) {
  const int bid = blockIdx.x;
  const int q = (bid < 256) ? bid : 767 - bid;   // CU-balanced (sum 9 tiles per CU pair)
  const int ktiles = (q >> 6) + 1;
  __shared__ unsigned short As[128 * 128];
  __shared__ unsigned short Bs[2][64 * 136];
  IDS4
  {  // swizzled As stage: rows=bh(128), 16 chunks/row
    const unsigned short* src = Qb + (long)q * DH;
#pragma unroll
    for (int it = 0; it < 8; ++it) {
      int n = tid + it * 256;
      int r = n >> 4, c = (n & 15) ^ (r & 7);
      gload16(src + (long)r * (T_ * DH) + c * 8, As + n * 8);
    }
  }
  f32x4 pv[8];
  const float* psrc = Pk + (long)q * T_ * DH;
  auto loadPk = [&](int kt) {
#pragma unroll
    for (int it = 0; it < 8; ++it) {
      int chunk = tid + it * 256;
      int r = chunk >> 5, c4 = (chunk & 31) * 4;
      pv[it] = *(const f32x4*)(psrc + (long)(kt * 64 + r) * DH + c4);
    }
  };
  auto writeB = [&](int buf) {
#pragma unroll
    for (int it = 0; it < 8; ++it) {
      int chunk = tid + it * 256;
      int r = chunk >> 5, c4 = (chunk & 31) * 4;
      ushort4v o;
      o.x = f2bf(pv[it].x); o.y = f2bf(pv[it].y); o.z = f2bf(pv[it].z); o.w = f2bf(pv[it].w);
      *(ushort4v*)&Bs[buf][r * 136 + c4] = o;
    }
  };
  loadPk(0);
  asm volatile("s_waitcnt vmcnt(0)" ::: "memory");   // As + Pk0 done
  writeB(0);
  asm volatile("s_waitcnt lgkmcnt(0)" ::: "memory");
  __builtin_amdgcn_s_barrier();
  for (int kt = 0; kt < ktiles; ++kt) {
    const bool pre = (kt + 1 < ktiles);
    if (pre) loadPk(kt + 1);
    f32x4 acc[4][2] = {};
#pragma unroll
    for (int ks = 0; ks < 4; ++ks) {
      short8 a[4], b[2];
#pragma unroll
      for (int i = 0; i < 4; ++i) {
        int ra = wm * 64 + i * 16 + lrow;
        int c = (ks * 4 + lg) ^ (ra & 7);
        a[i] = *(const short8*)&As[ra * 128 + c * 8];
      }
#pragma unroll
      for (int j = 0; j < 2; ++j)
        b[j] = *(const short8*)&Bs[kt & 1][(wn * 32 + j * 16 + lrow) * 136 + ks * 32 + lk8];
#pragma unroll
      for (int i = 0; i < 4; ++i)
#pragma unroll
        for (int j = 0; j < 2; ++j)
          acc[i][j] = mfma16(a[i], b[j], acc[i][j]);
    }
    if (pre) {
      asm volatile("s_waitcnt vmcnt(0)" ::: "memory");
      writeB((kt + 1) & 1);
    }
#pragma unroll
    for (int i = 0; i < 4; ++i)
#pragma unroll
      for (int j = 0; j < 2; ++j) {
        int k = kt * 64 + wn * 32 + j * 16 + lrow;
#pragma unroll
        for (int r = 0; r < 4; ++r) {
          int bh = wm * 64 + i * 16 + lr4 + r;
          att[((long)q * BH + bh) * T_ + k] = f2bf(acc[i][j][r]);
        }
      }
    asm volatile("s_waitcnt lgkmcnt(0)" ::: "memory");
    __builtin_amdgcn_s_barrier();
  }
}

// ------------------- FUSED QK^T + posk-bias + exp + PV: swapped QK (in-register softmax) -------------------
// mfma(K,Q) puts acc col=q, row=k: each lane holds 16 logits of ONE q-row -> exp in-register,
// rowsum via shfl_xor(16/32) over the 4-lane q-group, P~ written directly to Ps + att.
// No lt buffer (-17.4 KB LDS), 3 barriers/k-tile instead of 4.
__global__ __launch_bounds__(256) void k_qkv(const unsigned short* __restrict__ Qb,
                                             const unsigned short* __restrict__ Kb,
                                             const unsigned short* __restrict__ Vt,
                                             unsigned short* __restrict__ att,
                                             float* __restrict__ Sinv,
                                             unsigned short* __restrict__ Ybb) {
  const int bh = blockIdx.x & 127, pr = blockIdx.x >> 7;   // pr 0..3
  __shared__ unsigned short Qs[64 * 128], Ks[64 * 128], Vs[128 * 64];
  __shared__ unsigned short Ps[64 * 72];
  __shared__ float sInv[64];
  const int tid = threadIdx.x;
  const int lane = tid & 63, wid = tid >> 6;   // wid: q-16-group (QK) / (wm,wn) (PV)
  const int wm = wid >> 1, wn = wid & 1;
  const int lrow = lane & 15, lg = lane >> 4, lk8 = lg * 8, lr4 = lg * 4;
  const float scale = 0.08838834764831845f;   // 1/sqrt(128)
  const int b = bh >> 4, h = bh & 15;

  for (int pass = 0; pass < 2; ++pass) {
    const int qt = pass ? 7 - pr : pr;
    const int q0 = qt * 64, ktiles = qt + 1;
    const int qlane = q0 + wid * 16 + lrow;      // this lane's q row (QK/exp phase)
    unsigned short* arow = att + ((long)qlane * BH + bh) * T_;
    {
      const unsigned short* src = Qb + ((long)bh * T_ + q0) * DH;
#pragma unroll
      for (int it = 0; it < 4; ++it) {
        int n = tid + it * 256;
        int r = n >> 4, c = (n & 15) ^ (r & 7);
        gload16(src + (long)r * DH + c * 8, Qs + n * 8);
      }
    }
    float ssum = 0.f;
    f32x4 accv[2][4] = {};
    for (int kt = 0; kt < ktiles; ++kt) {
      const unsigned short* ksrc = Kb + ((long)bh * T_ + kt * 64) * DH;
#pragma unroll
      for (int it = 0; it < 4; ++it) {
        int n = tid + it * 256;
        int r = n >> 4, c = (n & 15) ^ (r & 7);
        gload16(ksrc + (long)r * DH + c * 8, Ks + n * 8);
      }
      const unsigned short* vsrc = Vt + (long)bh * DH * T_ + kt * 64;
#pragma unroll
      for (int it = 0; it < 4; ++it) {
        int n = tid + it * 256;
        int r = n >> 3, c = (n & 7) ^ (r & 7);
        gload16(vsrc + (long)r * T_ + c * 8, Vs + n * 8);
      }
      // bias prefetch: 4 x 8B per lane (this lane's own (q, k-slice) positions)
      ushort4v pb[4];
#pragma unroll
      for (int i = 0; i < 4; ++i)
        pb[i] = *(const ushort4v*)(arow + kt * 64 + i * 16 + lr4);
      __syncthreads();                       // drain staging, all tiles visible
      // ---- swapped QK^T: acc[i] covers k-rows i*16..i*16+15 for q-col = lrow ----
      f32x4 acc[4] = {};
#pragma unroll
      for (int ks = 0; ks < 4; ++ks) {
        int cq = (ks * 4 + lg) ^ (lrow & 7);
        short8 bq = *(const short8*)&Qs[(wid * 16 + lrow) * 128 + cq * 8];
#pragma unroll
        for (int i = 0; i < 4; ++i) {
          int ra = i * 16 + lrow;
          int c = (ks * 4 + lg) ^ (lrow & 7);
          short8 ak = *(const short8*)&Ks[ra * 128 + c * 8];
          acc[i] = mfma16(ak, bq, acc[i]);
        }
      }
      // ---- exp in-register + write Ptilde to att (global) and Ps (LDS) ----
#pragma unroll
      for (int i = 0; i < 4; ++i) {
        ushort4v o;
#pragma unroll
        for (int r = 0; r < 4; ++r) {
          int k = kt * 64 + i * 16 + lr4 + r;
          float e = (k <= qlane)
                    ? __expf((acc[i][r] + bf2f(pb[i][r])) * scale) : 0.f;
          o[r] = f2bf(e);
          ssum += e;
        }
        *(ushort4v*)(arow + kt * 64 + i * 16 + lr4) = o;
        *(ushort4v*)&Ps[(wid * 16 + lrow) * 72 + i * 16 + lr4] = o;
      }
      __syncthreads();                       // Ps visible; Ks/Qs reads done
      // ---- PV accumulate: Ps x Vs (wm/wn mapping) ----
#pragma unroll
      for (int ks = 0; ks < 2; ++ks) {
        short8 ap[2], bv2[4];
#pragma unroll
        for (int i = 0; i < 2; ++i) {
          int ra = wm * 32 + i * 16 + lrow;
          ap[i] = *(const short8*)&Ps[ra * 72 + ks * 32 + lk8];
        }
#pragma unroll
        for (int j = 0; j < 4; ++j) {
          int rb = wn * 64 + j * 16 + lrow;
          int c = ((ks * 4) + lg) ^ (rb & 7);
          bv2[j] = *(const short8*)&Vs[rb * 64 + c * 8];
        }
#pragma unroll
        for (int i = 0; i < 2; ++i)
#pragma unroll
          for (int j = 0; j < 4; ++j)
            accv[i][j] = mfma16(ap[i], bv2[j], accv[i][j]);
      }
      __syncthreads();                       // PV reads done before next kt restages
    }
    // row sums: reduce over the 4-lane q-group (lanes l, l^16, l^32, l^48)
    ssum += __shfl_xor(ssum, 16, 64);
    ssum += __shfl_xor(ssum, 32, 64);
    float si = 1.f / ssum;
    if (lg == 0) { sInv[wid * 16 + lrow] = si; Sinv[(long)qlane * BH + bh] = si; }
    __syncthreads();
#pragma unroll
    for (int i = 0; i < 2; ++i) {
      float sc2[4];
#pragma unroll
      for (int r = 0; r < 4; ++r) sc2[r] = sInv[wm * 32 + i * 16 + lr4 + r];
#pragma unroll
      for (int j = 0; j < 4; ++j) {
        int d = wn * 64 + j * 16 + lrow;
#pragma unroll
        for (int r = 0; r < 4; ++r) {
          int q = q0 + wm * 32 + i * 16 + lr4 + r;
          Ybb[(long)(b * T_ + q) * ND + h * DH + d] = f2bf(accv[i][j][r] * sc2[r]);
        }
      }
    }
    __syncthreads();                         // before next pass reuses Qs/Ks/Vs/sInv
  }
}

// ------------------- y += (Ptilde @ pos_v[q]) * Sinv; CU-balanced q; ping-pong Pv pipeline -------------------
__global__ __launch_bounds__(256) void k_posv(const unsigned short* __restrict__ P,
                                              const float* __restrict__ Pv,
                                              const float* __restrict__ Sinv,
                                              unsigned short* __restrict__ Ybb) {
  const int bid = blockIdx.x;
  const int q = (bid < 256) ? bid : 767 - bid;   // CU-balanced (sum 9 tiles per CU pair)
  const int ktiles = (q >> 6) + 1;
  __shared__ unsigned short As[128 * 64];
  __shared__ unsigned short Bs[2][128 * 72];
  __shared__ float lt[64 * LTQ];
  IDS4
  f32x4 pv[8];
  const float* psrc = Pv + (long)q * T_ * DH;
  auto loadPv = [&](int kt) {
#pragma unroll
    for (int it = 0; it < 8; ++it) {
      int chunk = tid + it * 256;
      int d4 = (chunk & 3) * 4 + ((chunk >> 6) & 7) * 16;
      int k  = ((chunk >> 2) & 15) + ((chunk >> 9) & 3) * 16;
      pv[it] = *(const f32x4*)(psrc + (long)(kt * 64 + k) * DH + d4);
    }
  };
  auto writeB = [&](int buf) {
#pragma unroll
    for (int it = 0; it < 8; ++it) {
      int chunk = tid + it * 256;
      int d4 = (chunk & 3) * 4 + ((chunk >> 6) & 7) * 16;
      int k  = ((chunk >> 2) & 15) + ((chunk >> 9) & 3) * 16;
      Bs[buf][(d4 + 0) * 72 + k] = f2bf(pv[it].x);
      Bs[buf][(d4 + 1) * 72 + k] = f2bf(pv[it].y);
      Bs[buf][(d4 + 2) * 72 + k] = f2bf(pv[it].z);
      Bs[buf][(d4 + 3) * 72 + k] = f2bf(pv[it].w);
    }
  };
  loadPv(0);
  asm volatile("s_waitcnt vmcnt(0)" ::: "memory");
  writeB(0);
  asm volatile("s_waitcnt lgkmcnt(0)" ::: "memory");
  __builtin_amdgcn_s_barrier();
  f32x4 acc[4][4] = {};
  for (int kt = 0; kt < ktiles; ++kt) {
    const bool pre = (kt + 1 < ktiles);
    stage_sw64<128>(As, P + (long)q * BH * T_ + kt * 64, T_, tid);    // 4 gloads swizzled
    if (pre) loadPv(kt + 1);                                          // 8 loads
    if (pre) asm volatile("s_waitcnt vmcnt(8)" ::: "memory");         // As done
    else     asm volatile("s_waitcnt vmcnt(0)" ::: "memory");
    __builtin_amdgcn_s_barrier();                                     // all As staged
    // A swizzled [128][64], B padded [128][72]
#pragma unroll
    for (int ks = 0; ks < 2; ++ks) {
      short8 a[4], b[4];
#pragma unroll
      for (int i = 0; i < 4; ++i) {
        int ra = wm * 64 + i * 16 + lrow;
        int c = (ks * 4 + lg) ^ (ra & 7);
        a[i] = *(const short8*)&As[ra * 64 + c * 8];
      }
#pragma unroll
      for (int j = 0; j < 4; ++j)
        b[j] = *(const short8*)&Bs[kt & 1][(wn * 64 + j * 16 + lrow) * 72 + ks * 32 + lk8];
#pragma unroll
      for (int i = 0; i < 4; ++i)
#pragma unroll
        for (int j = 0; j < 4; ++j)
          acc[i][j] = mfma16(a[i], b[j], acc[i][j]);
    }
    if (pre) {
      asm volatile("s_waitcnt vmcnt(0)" ::: "memory");
      writeB((kt + 1) & 1);
    }
    asm volatile("s_waitcnt lgkmcnt(0)" ::: "memory");
    __builtin_amdgcn_s_barrier();
  }
  // epilogue: 4 quarter-tiles (64bh x 64d) through padded scratch, vector RMW
  const int row = tid >> 2, c0 = (tid & 3) * 16;
#pragma unroll
  for (int hb = 0; hb < 2; ++hb)
#pragma unroll
    for (int hd = 0; hd < 2; ++hd) {
      int bh = hb * 64 + row;
      long idx = ((long)((bh >> 4) * T_ + q)) * ND + (bh & 15) * DH + hd * 64 + c0;
      short8 y0 = *(const short8*)&Ybb[idx];       // early issue
      short8 y1 = *(const short8*)&Ybb[idx + 8];
      float sc = Sinv[(long)q * BH + bh];
      if (wm == hb && wn == hd) {
#pragma unroll
        for (int i = 0; i < 4; ++i)
#pragma unroll
          for (int j = 0; j < 4; ++j)
#pragma unroll
            for (int r = 0; r < 4; ++r)
              lt[(i * 16 + lr4 + r) * LTQ + j * 16 + lrow] = acc[i][j][r];
      }
      __syncthreads();
      short8 o0, o1;
#pragma unroll
      for (int jj = 0; jj < 8; ++jj) {
        o0[jj] = (short)f2bf(lt[row * LTQ + c0 + jj] * sc + bf2f((unsigned short)y0[jj]));
        o1[jj] = (short)f2bf(lt[row * LTQ + c0 + 8 + jj] * sc + bf2f((unsigned short)y1[jj]));
      }
      *(short8*)&Ybb[idx] = o0;
      *(short8*)&Ybb[idx + 8] = o1;
      __syncthreads();
    }
}

// ------------------- out = Ybb @ Wp + bp: 128x128, swizzled operands, coalesced fp32 epilogue -------------------
__global__ __launch_bounds__(256) void k_oproj(const unsigned short* __restrict__ Ybb,
                                               const unsigned short* __restrict__ WpT,
                                               const float* __restrict__ bp,
                                               float* __restrict__ outp) {
  __shared__ unsigned short As[128 * 64], Bs[128 * 64];
  IDS4
  const int m0 = blockIdx.y * 128, n0 = blockIdx.x * 128;
  f32x4 acc[4][4] = {};
  for (int kk = 0; kk < ND; kk += 64) {
    stage_sw64<128>(As, Ybb + (long)m0 * ND + kk, ND, tid);
    stage_sw64<128>(Bs, WpT + (long)n0 * ND + kk, ND, tid);
    __syncthreads();
    mfma_sw64<4, 4>(As, Bs, wm * 64, wn * 64, lrow, lg, acc);
    __syncthreads();
  }
  float* lt = (float*)As;                 // [16][LTS]
  const int row = tid >> 4, c8 = (tid & 15) * 8;
  f32x4 b0 = *(const f32x4*)(bp + n0 + c8);
  f32x4 b1 = *(const f32x4*)(bp + n0 + c8 + 4);
#pragma unroll
  for (int rr = 0; rr < 8; ++rr) {
    if (wm == (rr >> 2)) {
      const int ii = rr & 3;
#pragma unroll
      for (int j = 0; j < 4; ++j)
#pragma unroll
        for (int r = 0; r < 4; ++r)
          lt[(lr4 + r) * LTS + wn * 64 + j * 16 + lrow] = acc[ii][j][r];
    }
    __syncthreads();
    f32x4 v0 = *(const f32x4*)&lt[row * LTS + c8];
    f32x4 v1 = *(const f32x4*)&lt[row * LTS + c8 + 4];
    int m = m0 + rr * 16 + row;
    v0.x += b0.x; v0.y += b0.y; v0.z += b0.z; v0.w += b0.w;
    v1.x += b1.x; v1.y += b1.y; v1.z += b1.z; v1.w += b1.w;
    *(f32x4*)&outp[(long)m * D_ + n0 + c8] = v0;
    *(f32x4*)&outp[(long)m * D_ + n0 + c8 + 4] = v1;
    __syncthreads();
  }
}

extern "C" void kernel_launch(void* const* d_in, const int* in_sizes, int n_in,
                              void* d_out, int out_size, void* d_ws, size_t ws_size,
                              hipStream_t stream) {
  const float* X  = (const float*)d_in[0];
  const float* Pk = (const float*)d_in[1];
  const float* Pv = (const float*)d_in[2];
  const float* Wq = (const float*)d_in[3];
  const float* bq = (const float*)d_in[4];
  const float* Wk = (const float*)d_in[5];
  const float* bk = (const float*)d_in[6];
  const float* Wv = (const float*)d_in[7];
  const float* bv = (const float*)d_in[8];
  const float* Wp = (const float*)d_in[9];
  const float* bp = (const float*)d_in[10];
  float* out = (float*)d_out;

  uint8_t* w = (uint8_t*)d_ws;
  unsigned short* Xb  = (unsigned short*)w; w += (size_t)BT * D_ * 2;      //  8 MB
  unsigned short* WT  = (unsigned short*)w; w += (size_t)3 * ND * D_ * 2;  // 12 MB
  unsigned short* WpT = (unsigned short*)w; w += (size_t)D_ * ND * 2;      //  4 MB
  unsigned short* Qb  = (unsigned short*)w; w += (size_t)BH * T_ * DH * 2; // 16 MB [bh][t][dh]
  unsigned short* Kb  = (unsigned short*)w; w += (size_t)BH * T_ * DH * 2; // 16 MB
  unsigned short* Vt  = (unsigned short*)w; w += (size_t)BH * DH * T_ * 2; // 16 MB [bh][dh][t]
  unsigned short* att = (unsigned short*)w; w += (size_t)T_ * BH * T_ * 2; // 67 MB
  unsigned short* Ybb = (unsigned short*)w; w += (size_t)BT * ND * 2;      // 16.7 MB
  float*          Sinv= (float*)w;          w += (size_t)T_ * BH * 4;      // 256 KB

  k_prep<<<12288, 256, 0, stream>>>(X, Xb, Wq, Wk, Wv, Wp, WT, WpT);
  k_proj8<<<1536, 256, 0, stream>>>(Xb, WT, bq, bk, bv, Qb, Kb, Vt);
  k_posk<<<T_, 256, 0, stream>>>(Qb, Pk, att);
  k_qkv<<<512, 256, 0, stream>>>(Qb, Kb, Vt, att, Sinv, Ybb);
  k_posv<<<T_, 256, 0, stream>>>(att, Pv, Sinv, Ybb);
  k_oproj<<<dim3(D_ / 128, BT / 128), 256, 0, stream>>>(Ybb, WpT, bp, out);
}